// Round 7
// baseline (2380.378 us; speedup 1.0000x reference)
//
#include <hip/hip_runtime.h>
#include <hip/hip_bf16.h>
#include <stdint.h>

#define BB 4
#define TT 64
#define NN 4096
#define HH 128
#define EE 65536
#define BN (BB*NN)   // 16384

typedef __attribute__((ext_vector_type(8))) short short8;
typedef __attribute__((ext_vector_type(4))) float f32x4;

__device__ __forceinline__ unsigned short bf16r(float f) {
    unsigned u = __float_as_uint(f);
    u += 0x7fffu + ((u >> 16) & 1u);
    return (unsigned short)(u >> 16);
}
__device__ __forceinline__ float bf2f(unsigned bits16) {
    return __uint_as_float(bits16 << 16);
}
__device__ __forceinline__ float sigm(float x) { return 1.f / (1.f + __expf(-x)); }
__device__ __forceinline__ float tanhfast(float x) {
    return 1.f - 2.f / (__expf(2.f * x) + 1.f);
}
// byte address within a [32][128]-bf16 LDS tile, XOR-swizzled
__device__ __forceinline__ unsigned swz(int row, int colbyte) {
    return (unsigned)(row * 256 + (colbyte ^ ((row & 7) << 4)));
}

// ================= packs =================
// WcbP: [half][nt(8)][ks(4)][lane(64)][8].  half0: Wc = W_msg@W_mix[0:128]; half1: W_mix[128:256]
__global__ void pack_wcb_kernel(const float* __restrict__ W_msg, const float* __restrict__ W_mix,
                                short* __restrict__ out)
{
    int idx = blockIdx.x * 256 + threadIdx.x;   // 4096
    if (idx >= 4096) return;
    int l = idx & 63, ks = (idx >> 6) & 3, nt = (idx >> 8) & 7, half = idx >> 11;
    int lo = l & 15, hi = l >> 4;
    int col = nt * 16 + lo;
    short8 v;
    #pragma unroll
    for (int i = 0; i < 8; ++i) {
        int k = ks * 32 + hi * 8 + i;
        float s;
        if (half == 0) {
            s = 0.f;
            for (int j = 0; j < 128; ++j) s += W_msg[k * 128 + j] * W_mix[j * 128 + col];
        } else {
            s = W_mix[(128 + k) * 128 + col];
        }
        v[i] = (short)bf16r(s);
    }
    *(short8*)(out + (size_t)idx * 8) = v;
}

// Wp4: 32 tiles x 8 ks. nt 0-7=r, 8-15=z (ks<4 Wih / ks>=4 Whh), 16-23=i_n (Wih,ks<4), 24-31=h_n (Whh,ks>=4)
__global__ void pack_ihh_kernel(const float* __restrict__ Wih, const float* __restrict__ Whh,
                                short* __restrict__ out)
{
    int idx = blockIdx.x * 256 + threadIdx.x;   // 16384
    if (idx >= 32 * 8 * 64) return;
    int l = idx & 63, ks = (idx >> 6) & 7, nt = idx >> 9;
    int lo = l & 15, hi = l >> 4;
    short8 v;
    #pragma unroll
    for (int i = 0; i < 8; ++i) {
        int k = ks * 32 + hi * 8 + i;
        float s = 0.f;
        if (nt < 16) {
            int col = nt * 16 + lo;
            s = (ks < 4) ? Wih[k * 384 + col] : Whh[(k - 128) * 384 + col];
        } else if (nt < 24) {
            int col = 256 + (nt - 16) * 16 + lo;
            s = (ks < 4) ? Wih[k * 384 + col] : 0.f;
        } else {
            int col = 256 + (nt - 24) * 16 + lo;
            s = (ks >= 4) ? Whh[(k - 128) * 384 + col] : 0.f;
        }
        v[i] = (short)bf16r(s);
    }
    *(short8*)(out + (size_t)idx * 8) = v;
}

__global__ void pack_bias_kernel(const float* __restrict__ b_ih, const float* __restrict__ b_hh,
                                 const float* __restrict__ b_msg, const float* __restrict__ W_mix,
                                 float* __restrict__ biasRZ, float* __restrict__ bvec)
{
    int j = threadIdx.x;
    biasRZ[j]       = b_ih[j]       + b_hh[j];
    biasRZ[128 + j] = b_ih[128 + j] + b_hh[128 + j];
    float s = 0.f;
    for (int jj = 0; jj < 128; ++jj) s += b_msg[jj] * W_mix[jj * 128 + j];
    bvec[j] = s;
}

// ================= x -> bf16 (all of it, once) =================
__global__ __launch_bounds__(256)
void cvt_all_kernel(const float* __restrict__ src, unsigned short* __restrict__ dst, long nchunk)
{
    long i = (long)blockIdx.x * 256 + threadIdx.x;
    long stride = (long)gridDim.x * 256;
    for (; i < nchunk; i += stride) {
        float4 v = *(const float4*)(src + i * 4);
        ushort4 o;
        o.x = bf16r(v.x); o.y = bf16r(v.y); o.z = bf16r(v.z); o.w = bf16r(v.w);
        *(ushort4*)(dst + i * 4) = o;
    }
}

// ================= gather for ALL (b,t): agg[bt,dst,:] = sum_src xb[bt,src,:] =================
__global__ __launch_bounds__(256)
void gather_all_kernel(const unsigned short* __restrict__ xb,
                       const int* __restrict__ off, const int* __restrict__ srcs,
                       unsigned short* __restrict__ agg)
{
    int rb = blockIdx.x * 4 + (threadIdx.x >> 6);   // 0 .. B*T*N-1
    int l = threadIdx.x & 63;
    int dst = rb & 4095;
    int bt  = rb >> 12;
    const unsigned short* __restrict__ xr = xb + (size_t)bt * NN * HH;
    int s = off[dst], e = off[dst + 1];
    float a0 = 0.f, a1 = 0.f, b0 = 0.f, b1 = 0.f;
    float c0 = 0.f, c1 = 0.f, d0 = 0.f, d1 = 0.f;
    int i = s;
    for (; i + 3 < e; i += 4) {
        int s0 = srcs[i], s1 = srcs[i + 1], s2 = srcs[i + 2], s3 = srcs[i + 3];
        unsigned v0 = *(const unsigned*)(xr + (size_t)s0 * HH + l * 2);
        unsigned v1 = *(const unsigned*)(xr + (size_t)s1 * HH + l * 2);
        unsigned v2 = *(const unsigned*)(xr + (size_t)s2 * HH + l * 2);
        unsigned v3 = *(const unsigned*)(xr + (size_t)s3 * HH + l * 2);
        a0 += bf2f(v0 & 0xffffu); a1 += bf2f(v0 >> 16);
        b0 += bf2f(v1 & 0xffffu); b1 += bf2f(v1 >> 16);
        c0 += bf2f(v2 & 0xffffu); c1 += bf2f(v2 >> 16);
        d0 += bf2f(v3 & 0xffffu); d1 += bf2f(v3 >> 16);
    }
    for (; i < e; ++i) {
        unsigned v0 = *(const unsigned*)(xr + (size_t)srcs[i] * HH + l * 2);
        a0 += bf2f(v0 & 0xffffu); a1 += bf2f(v0 >> 16);
    }
    a0 += b0 + c0 + d0; a1 += b1 + c1 + d1;
    *(unsigned*)(agg + (size_t)rb * HH + l * 2) = (unsigned)bf16r(a0) | ((unsigned)bf16r(a1) << 16);
}

// ================= persistent T-loop kernel, 32 rows/block, 2 blocks/CU =================
__global__ __launch_bounds__(512, 4)
void mega3_kernel(const unsigned short* __restrict__ xb,
                  const unsigned short* __restrict__ agg,
                  const short* __restrict__ WcbP, const short* __restrict__ Wp4,
                  const float* __restrict__ degf,
                  const float* __restrict__ bvec, const float* __restrict__ b_mix,
                  const float* __restrict__ biasRZ,
                  const float* __restrict__ b_ih, const float* __restrict__ b_hh,
                  const float* __restrict__ W_ro, const float* __restrict__ b_ro,
                  const float* __restrict__ targets, const void* __restrict__ maskp,
                  const int* __restrict__ flag,
                  float* __restrict__ lossBlock)
{
    __shared__ unsigned short sAgg[32 * 128];
    __shared__ unsigned short sX0[32 * 128];
    __shared__ unsigned short sX1[32 * 128];
    __shared__ unsigned short sMi[32 * 128];
    __shared__ unsigned short sSt[32 * 128];
    __shared__ float pP[8][32];
    __shared__ float sdeg[32];

    const int tid = threadIdx.x;
    const int w = tid >> 6, l = tid & 63, lo = l & 15, hi = l >> 4;
    const int nt = w;
    const int phys = blockIdx.x;
    const int b = phys >> 7;
    const int n0 = (phys & 127) * 32;

    // per-step-reloaded weight bases (stay hot in L2; frees ~128 VGPRs -> 2 blocks/CU)
    const short* wB0 = WcbP + ((size_t)(nt * 4) * 64 + l) * 8;        // + ks*512, ks=0..3
    const short* wB1 = WcbP + ((size_t)((8 + nt) * 4) * 64 + l) * 8;  // + (ks-4)*512
    const short* wRb = Wp4 + ((size_t)(nt * 8) * 64 + l) * 8;         // + ks*512
    const short* wZb = Wp4 + ((size_t)((8 + nt) * 8) * 64 + l) * 8;
    const short* wNb = Wp4 + ((size_t)((16 + nt) * 8) * 64 + l) * 8;  // ks=0..3
    const short* wHb = Wp4 + ((size_t)((24 + nt) * 8) * 64 + l) * 8;  // ks=4..7

    const int jcol = nt * 16 + lo;
    const float br = biasRZ[jcol], bz = biasRZ[128 + jcol];
    const float bi = b_ih[256 + jcol], bh = b_hh[256 + jcol];
    const float wro = W_ro[jcol];
    const float bv = bvec[jcol], bm = b_mix[jcol];
    const float bro = b_ro[0];
    const int fl = *flag;

    const int prow = tid >> 4, pc16 = tid & 15;    // staging: 1 short8 per thread per buffer

    // ---- prologue: stage t=0, zero state ----
    {
        size_t slab0 = ((size_t)(b * TT)) * NN * HH + (size_t)(n0 + prow) * HH + pc16 * 8;
        short8 vx = *(const short8*)(xb + slab0);
        short8 va = *(const short8*)(agg + slab0);
        *(short8*)((char*)sX0 + swz(prow, pc16 * 16)) = vx;
        *(short8*)((char*)sAgg + swz(prow, pc16 * 16)) = va;
    }
    #pragma unroll
    for (int it = 0; it < 4; ++it) ((unsigned*)sSt)[tid + it * 512] = 0u;
    if (tid < 32) sdeg[tid] = degf[n0 + tid];
    float lossAcc = 0.f;
    __syncthreads();

    unsigned short* sXc = sX0;
    unsigned short* sXn = sX1;

    for (int t = 0; t < TT; ++t) {
        // ---- prefetch next step's staging into registers (latency hides under B+C) ----
        const int tn = (t < TT - 1) ? t + 1 : t;
        const size_t slabn = ((size_t)(b * TT + tn)) * NN * HH + (size_t)(n0 + prow) * HH + pc16 * 8;
        short8 rx = *(const short8*)(xb + slabn);
        short8 ra = *(const short8*)(agg + slabn);

        // ---- B: mi = agg@Wc + state@Wb + deg*bvec + b_mix ----
        f32x4 mAcc[2] = {};
        #pragma unroll
        for (int ks = 0; ks < 8; ++ks) {
            short8 bw = (ks < 4) ? *(const short8*)(wB0 + ks * 512)
                                 : *(const short8*)(wB1 + (ks - 4) * 512);
            #pragma unroll
            for (int s4 = 0; s4 < 2; ++s4) {
                short8 af = (ks < 4)
                    ? *(const short8*)((const char*)sAgg + swz(s4 * 16 + lo, ks * 64 + hi * 16))
                    : *(const short8*)((const char*)sSt + swz(s4 * 16 + lo, (ks - 4) * 64 + hi * 16));
                mAcc[s4] = __builtin_amdgcn_mfma_f32_16x16x32_bf16(af, bw, mAcc[s4], 0, 0, 0);
            }
        }
        #pragma unroll
        for (int s4 = 0; s4 < 2; ++s4)
            #pragma unroll
            for (int q = 0; q < 4; ++q) {
                int row = s4 * 16 + hi * 4 + q;
                float v = mAcc[s4][q] + sdeg[row] * bv + bm;
                unsigned bits = bf16r(v);
                unsigned other = (unsigned)__shfl_xor((int)bits, 1);
                if (!(lo & 1))
                    *(unsigned*)((char*)sMi + swz(row, jcol * 2)) = bits | (other << 16);
            }
        __syncthreads();   // bar A

        // ---- C: R/Z (K=256), N (K=128, A=mi), H (K=128, A=sXc) ----
        f32x4 aR[2] = {}, aZ[2] = {}, aN2[2] = {}, aH2[2] = {};
        #pragma unroll
        for (int ks = 0; ks < 8; ++ks) {
            short8 af[2];
            #pragma unroll
            for (int s4 = 0; s4 < 2; ++s4)
                af[s4] = (ks < 4)
                    ? *(const short8*)((const char*)sMi + swz(s4 * 16 + lo, ks * 64 + hi * 16))
                    : *(const short8*)((const char*)sXc + swz(s4 * 16 + lo, (ks - 4) * 64 + hi * 16));
            short8 bR = *(const short8*)(wRb + ks * 512);
            #pragma unroll
            for (int s4 = 0; s4 < 2; ++s4)
                aR[s4] = __builtin_amdgcn_mfma_f32_16x16x32_bf16(af[s4], bR, aR[s4], 0, 0, 0);
            short8 bZ = *(const short8*)(wZb + ks * 512);
            #pragma unroll
            for (int s4 = 0; s4 < 2; ++s4)
                aZ[s4] = __builtin_amdgcn_mfma_f32_16x16x32_bf16(af[s4], bZ, aZ[s4], 0, 0, 0);
            if (ks < 4) {
                short8 bN = *(const short8*)(wNb + ks * 512);
                #pragma unroll
                for (int s4 = 0; s4 < 2; ++s4)
                    aN2[s4] = __builtin_amdgcn_mfma_f32_16x16x32_bf16(af[s4], bN, aN2[s4], 0, 0, 0);
            } else {
                short8 bH = *(const short8*)(wHb + ks * 512);
                #pragma unroll
                for (int s4 = 0; s4 < 2; ++s4)
                    aH2[s4] = __builtin_amdgcn_mfma_f32_16x16x32_bf16(af[s4], bH, aH2[s4], 0, 0, 0);
            }
        }

        // ---- stage-write t+1 (sAgg consumer done at bar A; sXn is the other buffer) ----
        if (t < TT - 1) {
            *(short8*)((char*)sAgg + swz(prow, pc16 * 16)) = ra;
            *(short8*)((char*)sXn + swz(prow, pc16 * 16)) = rx;
        }

        // ---- D: gates, state write (packed u32), W_ro partial dot ----
        float pacc[2][4];
        #pragma unroll
        for (int s4 = 0; s4 < 2; ++s4)
            #pragma unroll
            for (int q = 0; q < 4; ++q) {
                int row = s4 * 16 + hi * 4 + q;
                float rg = sigm(aR[s4][q] + br);
                float zg = sigm(aZ[s4][q] + bz);
                float ng = tanhfast(aN2[s4][q] + bi + rg * (aH2[s4][q] + bh));
                float xv = bf2f(*(const unsigned short*)((const char*)sXc + swz(row, jcol * 2)));
                float ns = (1.f - zg) * ng + zg * xv;
                unsigned bits = bf16r(ns);
                unsigned other = (unsigned)__shfl_xor((int)bits, 1);
                if (!(lo & 1))
                    *(unsigned*)((char*)sSt + swz(row, jcol * 2)) = bits | (other << 16);
                pacc[s4][q] = ns * wro;
            }
        #pragma unroll
        for (int o = 1; o < 16; o <<= 1)
            #pragma unroll
            for (int s4 = 0; s4 < 2; ++s4)
                #pragma unroll
                for (int q = 0; q < 4; ++q)
                    pacc[s4][q] += __shfl_xor(pacc[s4][q], o);
        if (lo == 0) {
            #pragma unroll
            for (int s4 = 0; s4 < 2; ++s4)
                #pragma unroll
                for (int q = 0; q < 4; ++q)
                    pP[w][s4 * 16 + hi * 4 + q] = pacc[s4][q];
        }
        __syncthreads();   // bar B

        // ---- loss consume (lanes 0-31 of wave 0) ----
        if (tid < 32) {
            int row = tid;
            float out = bro;
            #pragma unroll
            for (int ww = 0; ww < 8; ++ww) out += pP[ww][row];
            size_t ti = ((size_t)(b * TT + t)) * NN + (n0 + row);
            float tgt = targets[ti];
            float mv = fl ? (((const unsigned char*)maskp)[ti] ? 1.f : 0.f)
                          : (((const int*)maskp)[ti] ? 1.f : 0.f);
            float d = out - tgt;
            lossAcc += 0.5f * d * d * mv;
        }

        unsigned short* tmp = sXc; sXc = sXn; sXn = tmp;
    }

    if (tid < 32) {
        float v = lossAcc;
        #pragma unroll
        for (int o = 1; o < 32; o <<= 1) v += __shfl_xor(v, o);
        if (tid == 0) lossBlock[phys] = v;
    }
}

// ================= CSR build =================
__global__ void count_kernel(const int* __restrict__ dst, int* __restrict__ counts)
{
    int e = blockIdx.x * 256 + threadIdx.x;
    if (e < EE) atomicAdd(&counts[dst[e]], 1);
}

__global__ __launch_bounds__(1024)
void scan_kernel(const int* __restrict__ counts, int* __restrict__ off, int* __restrict__ cursor,
                 float* __restrict__ degf)
{
    __shared__ int s[1024];
    int tid = threadIdx.x;
    int base = tid * 4;
    int c[4]; int sum = 0;
    #pragma unroll
    for (int i = 0; i < 4; ++i) { c[i] = counts[base + i]; sum += c[i]; }
    s[tid] = sum; __syncthreads();
    for (int o = 1; o < 1024; o <<= 1) {
        int v = (tid >= o) ? s[tid - o] : 0;
        __syncthreads();
        s[tid] += v;
        __syncthreads();
    }
    int incl = s[tid];
    int run = incl - sum;
    #pragma unroll
    for (int i = 0; i < 4; ++i) {
        off[base + i] = run; cursor[base + i] = run;
        degf[base + i] = (float)c[i];
        run += c[i];
    }
    if (tid == 1023) off[4096] = incl;
}

__global__ void fill_kernel(const int* __restrict__ src, const int* __restrict__ dst,
                            int* __restrict__ cursor, int* __restrict__ csr_src)
{
    int e = blockIdx.x * 256 + threadIdx.x;
    if (e < EE) {
        int d = dst[e];
        int pos = atomicAdd(&cursor[d], 1);
        csr_src[pos] = src[e];
    }
}

// ================= mask detect / masked count =================
__global__ void detect_kernel(const unsigned char* __restrict__ maskb, int* __restrict__ flag)
{
    int i = blockIdx.x * 256 + threadIdx.x;
    bool hit = (i < BB * TT * NN) && (i & 3) && maskb[i];
    if (__any(hit) && (threadIdx.x & 63) == 0) atomicOr(flag, 1);
}

__global__ void masksum_kernel(const void* __restrict__ maskp, const int* __restrict__ flag,
                               float* __restrict__ den)
{
    int i = blockIdx.x * 256 + threadIdx.x;
    float v = 0.f;
    if (i < BB * TT * NN) {
        if (*flag) v = ((const unsigned char*)maskp)[i] ? 1.f : 0.f;
        else       v = ((const int*)maskp)[i] ? 1.f : 0.f;
    }
    #pragma unroll
    for (int o = 32; o > 0; o >>= 1) v += __shfl_down(v, o);
    __shared__ float sm[4];
    if ((threadIdx.x & 63) == 0) sm[threadIdx.x >> 6] = v;
    __syncthreads();
    if (threadIdx.x == 0) atomicAdd(den, sm[0] + sm[1] + sm[2] + sm[3]);
}

// ================= final reduce + dual-dtype output =================
__global__ __launch_bounds__(256)
void final_kernel(const float* __restrict__ lossBlock, const float* __restrict__ den,
                  unsigned* __restrict__ out)
{
    __shared__ float s[256];
    float v = lossBlock[threadIdx.x] + lossBlock[256 + threadIdx.x];
    s[threadIdx.x] = v;
    __syncthreads();
    for (int o = 128; o > 0; o >>= 1) {
        if (threadIdx.x < o) s[threadIdx.x] += s[threadIdx.x + o];
        __syncthreads();
    }
    if (threadIdx.x == 0) {
        float L = s[0] / den[0];
        unsigned u = __float_as_uint(L);
        u += 0x7fffu + ((u >> 16) & 1u);
        unsigned hi = u >> 16;
        out[0] = hi * 0x10001u;   // bf16-exact low half; ~bf16 value as f32
    }
}

extern "C" void kernel_launch(void* const* d_in, const int* in_sizes, int n_in,
                              void* d_out, int out_size, void* d_ws, size_t ws_size,
                              hipStream_t stream)
{
    const float* x       = (const float*)d_in[0];
    const float* targets = (const float*)d_in[1];
    const float* W_msg   = (const float*)d_in[2];
    const float* b_msg   = (const float*)d_in[3];
    const float* W_mix   = (const float*)d_in[4];
    const float* b_mix   = (const float*)d_in[5];
    const float* W_ih    = (const float*)d_in[6];
    const float* b_ih    = (const float*)d_in[7];
    const float* W_hh    = (const float*)d_in[8];
    const float* b_hh    = (const float*)d_in[9];
    const float* W_ro    = (const float*)d_in[10];
    const float* b_ro    = (const float*)d_in[11];
    const void*  maskp   = d_in[12];
    const int*   esrc    = (const int*)d_in[13];
    const int*   edst    = (const int*)d_in[14];

    char* ws = (char*)d_ws;
    unsigned short* xb  = (unsigned short*)ws; ws += (size_t)BB * TT * NN * HH * 2;  // 268 MB
    unsigned short* agg = (unsigned short*)ws; ws += (size_t)BB * TT * NN * HH * 2;  // 268 MB
    short* WcbP        = (short*)ws; ws += (size_t)4096 * 8 * 2;
    short* Wp4         = (short*)ws; ws += (size_t)32 * 8 * 64 * 8 * 2;
    float* biasRZ      = (float*)ws; ws += 256 * 4;
    float* bvec        = (float*)ws; ws += 128 * 4;
    float* degf        = (float*)ws; ws += 4096 * 4;
    float* lossBlock   = (float*)ws; ws += 512 * 4;
    int*   csr_off     = (int*)ws;   ws += 4104 * 4;
    int*   cursor      = (int*)ws;   ws += 4096 * 4;
    int*   counts      = (int*)ws;   ws += 4096 * 4;
    int*   csr_src     = (int*)ws;   ws += (size_t)EE * 4;
    int*   flag        = (int*)ws;   ws += 64;
    float* den         = (float*)ws; ws += 64;

    hipMemsetAsync(counts, 0, 4096 * 4, stream);
    hipMemsetAsync(flag, 0, 64, stream);
    hipMemsetAsync(den, 0, 4, stream);

    detect_kernel   <<<4096, 256, 0, stream>>>((const unsigned char*)maskp, flag);
    masksum_kernel  <<<4096, 256, 0, stream>>>(maskp, flag, den);
    count_kernel    <<<EE / 256, 256, 0, stream>>>(edst, counts);
    scan_kernel     <<<1, 1024, 0, stream>>>(counts, csr_off, cursor, degf);
    fill_kernel     <<<EE / 256, 256, 0, stream>>>(esrc, edst, cursor, csr_src);
    pack_wcb_kernel <<<16, 256, 0, stream>>>(W_msg, W_mix, WcbP);
    pack_ihh_kernel <<<64, 256, 0, stream>>>(W_ih, W_hh, Wp4);
    pack_bias_kernel<<<1, 128, 0, stream>>>(b_ih, b_hh, b_msg, W_mix, biasRZ, bvec);

    cvt_all_kernel  <<<2048, 256, 0, stream>>>(x, xb, (long)BB * TT * NN * HH / 4);
    gather_all_kernel<<<(BB * TT * NN) / 4, 256, 0, stream>>>(xb, csr_off, csr_src, agg);

    mega3_kernel<<<512, 512, 0, stream>>>(xb, agg, WcbP, Wp4, degf, bvec, b_mix, biasRZ,
                                          b_ih, b_hh, W_ro, b_ro, targets, maskp, flag,
                                          lossBlock);
    final_kernel<<<1, 256, 0, stream>>>(lossBlock, den, (unsigned*)d_out);
}